// Round 3
// baseline (16069.357 us; speedup 1.0000x reference)
//
#include <hip/hip_runtime.h>
#include <hip/hip_bf16.h>

// Problem constants (n=4, c=512, h=w=64)
#define NBATCH 4
#define C 512
#define HW 4096        // h*w = sequence length
#define GROUPS 32
#define D3 1536        // 3*C
#define EPSV 1e-5f
#define ATTN_SCALE 0.044194173824159216f  // 1/sqrt(512)

// Workspace layout (total 8,389,632 B ~= 8.0 MiB + 1 KiB):
//   [0, 1024)            : stats  (mean[128] | rstd[128]) fp32
//   [1024, 1024+8 MiB)   : KV bf16, per-batch: KV[t][0..511]=K, [512..1023]=V
// Keep this SMALL — ws_size is unknown and earlier 12.6/42 MB versions NaN'd,
// possibly from overrunning d_ws.

// ---------------------------------------------------------------------------
// Runtime dtype detection: harness may store tensors as bf16 OR fp32.
// Interpret the first 64 uint16 of w_in as bf16. Genuine bf16 weights are
// |v| < 0.3 (N(0, 1/512) scale). If storage is fp32, half of those uint16 are
// random mantissa bits whose bf16 interpretation is huge or NaN with
// probability ~0.5 each -> flag fp32. P(misdetect) ~ (0.5)^32.
// ---------------------------------------------------------------------------
__device__ __forceinline__ float bf16bits(unsigned short h) {
  return __uint_as_float(((unsigned)h) << 16);
}
__device__ __forceinline__ bool detect_f32(const void* w_in) {
  const unsigned short* u = (const unsigned short*)w_in;
  bool f32 = false;
#pragma unroll
  for (int i = 0; i < 64; ++i) {
    float v = bf16bits(u[i]);
    if (!(fabsf(v) < 1e3f)) f32 = true;  // NaN -> true
  }
  return f32;
}
__device__ __forceinline__ float ld(const void* p, size_t i, bool f32) {
  if (f32) return ((const float*)p)[i];
  return bf16bits(((const unsigned short*)p)[i]);
}
__device__ __forceinline__ void unpack8(uint4 w, float* f) {
  f[0] = __uint_as_float(w.x << 16);
  f[1] = __uint_as_float(w.x & 0xFFFF0000u);
  f[2] = __uint_as_float(w.y << 16);
  f[3] = __uint_as_float(w.y & 0xFFFF0000u);
  f[4] = __uint_as_float(w.z << 16);
  f[5] = __uint_as_float(w.z & 0xFFFF0000u);
  f[6] = __uint_as_float(w.w << 16);
  f[7] = __uint_as_float(w.w & 0xFFFF0000u);
}

// ---------------------------------------------------------------------------
// Kernel 1: GroupNorm statistics. One block per (batch, group); the group
// region is contiguous: 16 channels * 4096 = 65536 elements.
// ---------------------------------------------------------------------------
__global__ __launch_bounds__(256) void gn_stats_kernel(
    const void* __restrict__ x, const void* __restrict__ w_in,
    float* __restrict__ stats) {
  const bool f32 = detect_f32(w_in);
  const int b = blockIdx.x;  // nn*32 + g
  const size_t base = (size_t)b << 16;
  float s = 0.f, ss = 0.f;
  for (int i = threadIdx.x; i < 65536; i += 256) {
    float v = ld(x, base + i, f32);
    s += v;
    ss += v * v;
  }
  __shared__ float rs[256], rq[256];
  rs[threadIdx.x] = s;
  rq[threadIdx.x] = ss;
  __syncthreads();
  for (int off = 128; off > 0; off >>= 1) {
    if (threadIdx.x < off) {
      rs[threadIdx.x] += rs[threadIdx.x + off];
      rq[threadIdx.x] += rq[threadIdx.x + off];
    }
    __syncthreads();
  }
  if (threadIdx.x == 0) {
    float m = rs[0] * (1.0f / 65536.0f);
    float var = rq[0] * (1.0f / 65536.0f) - m * m;
    stats[b] = m;
    stats[128 + b] = rsqrtf(var + EPSV);
  }
}

// ---------------------------------------------------------------------------
// Kernel 2: fused GroupNorm + K/V GEMM (per batch), bf16 output into ws.
// kv[t][e] = sum_c GN(x[nn][c][t]) * w_in[512+e][c] + b_in[512+e], e in [0,1024)
// M=4096 (t), N=1024 (e), K=512. Tile 64x64, BK=16, 256 thr, 4x4/thread.
// ---------------------------------------------------------------------------
__global__ __launch_bounds__(256) void kv_gemm_kernel(
    const void* __restrict__ x, const void* __restrict__ gsc,
    const void* __restrict__ gbi, const float* __restrict__ stats,
    const void* __restrict__ w_in, const void* __restrict__ b_in,
    __hip_bfloat16* __restrict__ kv, int nn) {
  const bool f32 = detect_f32(w_in);
  const int tid = threadIdx.x;
  const int tx = tid & 15, ty = tid >> 4;
  const int tBase = blockIdx.y * 64;  // t (spatial)
  const int nBase = blockIdx.x * 64;  // e (kv column)
  __shared__ float As[16][64];
  __shared__ float Bs[16][64];
  float acc[4][4] = {};
  for (int k0 = 0; k0 < 512; k0 += 16) {
#pragma unroll
    for (int l = 0; l < 4; ++l) {
      int lin = tid + 256 * l;
      int kk = lin >> 6, m = lin & 63;
      int ch = k0 + kk;
      float mu = stats[nn * GROUPS + (ch >> 4)];
      float rr = stats[128 + nn * GROUPS + (ch >> 4)];
      float v = ld(x, ((size_t)(nn * C + ch) << 12) + tBase + m, f32);
      As[kk][m] = (v - mu) * rr * ld(gsc, ch, f32) + ld(gbi, ch, f32);
    }
#pragma unroll
    for (int l = 0; l < 4; ++l) {
      int lin = tid + 256 * l;
      int n = lin >> 4, kk = lin & 15;
      Bs[kk][n] = ld(w_in, (size_t)(512 + nBase + n) * 512 + k0 + kk, f32);
    }
    __syncthreads();
#pragma unroll
    for (int kk = 0; kk < 16; ++kk) {
      float a[4], b[4];
#pragma unroll
      for (int i = 0; i < 4; ++i) a[i] = As[kk][ty * 4 + i];
#pragma unroll
      for (int j = 0; j < 4; ++j) b[j] = Bs[kk][tx * 4 + j];
#pragma unroll
      for (int i = 0; i < 4; ++i)
#pragma unroll
        for (int j = 0; j < 4; ++j) acc[i][j] += a[i] * b[j];
    }
    __syncthreads();
  }
#pragma unroll
  for (int i = 0; i < 4; ++i) {
    int t = tBase + ty * 4 + i;
#pragma unroll
    for (int j = 0; j < 4; ++j) {
      int col = nBase + tx * 4 + j;
      kv[(size_t)t * 1024 + col] =
          __float2bfloat16(acc[i][j] + ld(b_in, 512 + col, f32));
    }
  }
}

// ---------------------------------------------------------------------------
// Kernel 3: fused q-compute + attention + out-projection + residual.
// One block (256 threads) per query position s. No Q / attn buffers needed.
// ---------------------------------------------------------------------------
__global__ __launch_bounds__(256) void attn_proj_kernel(
    const void* __restrict__ x, const void* __restrict__ gsc,
    const void* __restrict__ gbi, const float* __restrict__ stats,
    const void* __restrict__ w_in, const void* __restrict__ b_in,
    const __hip_bfloat16* __restrict__ kv, const void* __restrict__ w_out,
    const void* __restrict__ b_out, void* __restrict__ out, int nn) {
  const bool f32 = detect_f32(w_in);
  const int s = blockIdx.x;
  const int tid = threadIdx.x;
  __shared__ float S[512];     // normalized channel vector at spatial s
  __shared__ float qrow[512];  // q (scaled, biased)
  __shared__ float orow[512];  // attention output row
  __shared__ float red[256];
  __shared__ float sc[4096];

  // --- normalized input column S[c] = GN(x[nn][c][s]) ---
#pragma unroll
  for (int half = 0; half < 2; ++half) {
    int c = tid + 256 * half;
    float mu = stats[nn * GROUPS + (c >> 4)];
    float rr = stats[128 + nn * GROUPS + (c >> 4)];
    float v = ld(x, ((size_t)(nn * C + c) << 12) + s, f32);
    S[c] = (v - mu) * rr * ld(gsc, c, f32) + ld(gbi, c, f32);
  }
  __syncthreads();

  // --- q[e] = (S . w_in[e][:] + b_in[e]) * scale , e = tid, tid+256 ---
#pragma unroll
  for (int half = 0; half < 2; ++half) {
    int e = tid + 256 * half;
    float acc = 0.f;
    if (f32) {
      const float4* w4 =
          reinterpret_cast<const float4*>((const float*)w_in + (size_t)e * 512);
      for (int i = 0; i < 128; ++i) {
        float4 w = w4[i];
        acc += w.x * S[4 * i] + w.y * S[4 * i + 1] + w.z * S[4 * i + 2] +
               w.w * S[4 * i + 3];
      }
    } else {
      const uint4* w4 = reinterpret_cast<const uint4*>(
          (const unsigned short*)w_in + (size_t)e * 512);
      for (int i = 0; i < 64; ++i) {
        float f[8];
        unpack8(w4[i], f);
#pragma unroll
        for (int j = 0; j < 8; ++j) acc += f[j] * S[8 * i + j];
      }
    }
    qrow[e] = (acc + ld(b_in, e, f32)) * ATTN_SCALE;
  }
  __syncthreads();

  // --- scores sc[t] = qrow . K[t]  (KV is bf16 always) ---
#pragma unroll 1
  for (int i = 0; i < 16; ++i) {
    int t = tid + 256 * i;
    const uint4* k4 = reinterpret_cast<const uint4*>(kv + (size_t)t * 1024);
    float acc = 0.f;
#pragma unroll 4
    for (int d = 0; d < 64; ++d) {
      float f[8];
      unpack8(k4[d], f);
#pragma unroll
      for (int j = 0; j < 8; ++j) acc += f[j] * qrow[8 * d + j];
    }
    sc[t] = acc;
  }
  __syncthreads();

  // --- softmax over sc ---
  float m = -3.0e38f;
#pragma unroll
  for (int i = 0; i < 16; ++i) m = fmaxf(m, sc[tid + 256 * i]);
  red[tid] = m;
  __syncthreads();
  for (int off = 128; off > 0; off >>= 1) {
    if (tid < off) red[tid] = fmaxf(red[tid], red[tid + off]);
    __syncthreads();
  }
  m = red[0];
  __syncthreads();
  float lsum = 0.f;
#pragma unroll
  for (int i = 0; i < 16; ++i) {
    int t = tid + 256 * i;
    float e = __expf(sc[t] - m);
    sc[t] = e;
    lsum += e;
  }
  red[tid] = lsum;
  __syncthreads();
  for (int off = 128; off > 0; off >>= 1) {
    if (tid < off) red[tid] += red[tid + off];
    __syncthreads();
  }
  float inv = 1.0f / red[0];
  __syncthreads();
#pragma unroll
  for (int i = 0; i < 16; ++i) sc[tid + 256 * i] *= inv;
  __syncthreads();

  // --- P @ V : thread owns channels tid, tid+256 (coalesced V reads) ---
  {
    float a0 = 0.f, a1 = 0.f;
    const __hip_bfloat16* vb = kv + 512;
#pragma unroll 4
    for (int t = 0; t < 4096; ++t) {
      float p = sc[t];
      a0 += p * __bfloat162float(vb[(size_t)t * 1024 + tid]);
      a1 += p * __bfloat162float(vb[(size_t)t * 1024 + tid + 256]);
    }
    orow[tid] = a0;
    orow[tid + 256] = a1;
  }
  __syncthreads();

  // --- out[nn][cc][s] = orow . w_out[cc][:] + b_out[cc] + x[nn][cc][s] ---
#pragma unroll
  for (int half = 0; half < 2; ++half) {
    int cc = tid + 256 * half;
    float acc = 0.f;
    if (f32) {
      const float4* w4 = reinterpret_cast<const float4*>((const float*)w_out +
                                                         (size_t)cc * 512);
      for (int i = 0; i < 128; ++i) {
        float4 w = w4[i];
        acc += w.x * orow[4 * i] + w.y * orow[4 * i + 1] +
               w.z * orow[4 * i + 2] + w.w * orow[4 * i + 3];
      }
    } else {
      const uint4* w4 = reinterpret_cast<const uint4*>(
          (const unsigned short*)w_out + (size_t)cc * 512);
      for (int i = 0; i < 64; ++i) {
        float f[8];
        unpack8(w4[i], f);
#pragma unroll
        for (int j = 0; j < 8; ++j) acc += f[j] * orow[8 * i + j];
      }
    }
    size_t oidx = ((size_t)(nn * C + cc) << 12) + s;
    float v = acc + ld(b_out, cc, f32) + ld(x, oidx, f32);
    if (f32)
      ((float*)out)[oidx] = v;
    else
      ((unsigned short*)out)[oidx] = (unsigned short)(__float_as_uint(
          v) >> 16) /* truncate */, ((__hip_bfloat16*)out)[oidx] =
                                        __float2bfloat16(v);
  }
}

// ---------------------------------------------------------------------------
extern "C" void kernel_launch(void* const* d_in, const int* in_sizes, int n_in,
                              void* d_out, int out_size, void* d_ws, size_t ws_size,
                              hipStream_t stream) {
  const void* x = d_in[0];
  const void* gn_scale = d_in[1];
  const void* gn_bias = d_in[2];
  const void* w_in = d_in[3];
  const void* b_in = d_in[4];
  const void* w_out = d_in[5];
  const void* b_out = d_in[6];
  (void)in_sizes; (void)n_in; (void)out_size; (void)ws_size;

  float* stats = (float*)d_ws;                                  // 1 KB
  __hip_bfloat16* kv = (__hip_bfloat16*)((char*)d_ws + 1024);   // 8 MiB

  gn_stats_kernel<<<NBATCH * GROUPS, 256, 0, stream>>>(x, w_in, stats);

  for (int nn = 0; nn < NBATCH; ++nn) {
    kv_gemm_kernel<<<dim3(16, 64), 256, 0, stream>>>(x, gn_scale, gn_bias,
                                                     stats, w_in, b_in, kv, nn);
    attn_proj_kernel<<<HW, 256, 0, stream>>>(x, gn_scale, gn_bias, stats, w_in,
                                             b_in, kv, w_out, b_out, d_out, nn);
  }
}

// Round 8
// 15620.927 us; speedup vs baseline: 1.0287x; 1.0287x over previous
//
#include <hip/hip_runtime.h>
#include <hip/hip_bf16.h>

// n=4, c=512, h=w=64. Reference declares float32; harness dtype resolved at
// RUNTIME via detect_f32 (R3-proven). Evidence: every hard-coded-bf16 round
// (R1,R4,R5,R6,R7) NaN'd; the detect_f32 round (R3) passed.
#define NBATCH 4
#define C 512
#define HW 4096
#define GROUPS 32
#define EPSV 1e-5f
#define ATTN_SCALE 0.044194173824159216f  // 1/sqrt(512)

typedef short bf16x8 __attribute__((ext_vector_type(8)));  // 8 bf16 = 4 VGPR
typedef float f32x4 __attribute__((ext_vector_type(4)));

__device__ __forceinline__ float bf(unsigned short u) {
  return __uint_as_float(((unsigned)u) << 16);
}
__device__ __forceinline__ unsigned short fb(float v) {
  __hip_bfloat16 h = __float2bfloat16(v);
  return *(unsigned short*)&h;
}
__device__ __forceinline__ bf16x8 frag_ld(const short* p) {
  return *(const bf16x8*)p;  // 16B-aligned by construction
}
#define MFMA(a, b, c) __builtin_amdgcn_mfma_f32_16x16x32_bf16((a), (b), (c), 0, 0, 0)

__device__ __forceinline__ void unpack8(uint4 w, float* f) {
  f[0] = __uint_as_float(w.x << 16);
  f[1] = __uint_as_float(w.x & 0xFFFF0000u);
  f[2] = __uint_as_float(w.y << 16);
  f[3] = __uint_as_float(w.y & 0xFFFF0000u);
  f[4] = __uint_as_float(w.z << 16);
  f[5] = __uint_as_float(w.z & 0xFFFF0000u);
  f[6] = __uint_as_float(w.w << 16);
  f[7] = __uint_as_float(w.w & 0xFFFF0000u);
}

// Runtime dtype detection (R3-proven). bf16 weights: |v|<0.3 always. fp32
// storage: the 32 mantissa-half u16s are huge/NaN as bf16 w.p. ~0.46 each.
__device__ __forceinline__ bool detect_f32(const void* w_in) {
  const unsigned short* u = (const unsigned short*)w_in;
  bool f32 = false;
#pragma unroll
  for (int i = 0; i < 64; ++i) {
    float v = bf(u[i]);
    if (!(fabsf(v) < 1e3f)) f32 = true;  // NaN -> true
  }
  return f32;
}
__device__ __forceinline__ float ld(const void* p, size_t i, bool f32) {
  if (f32) return ((const float*)p)[i];
  return bf(((const unsigned short*)p)[i]);
}

// ---------------------------------------------------------------------------
// GroupNorm stats — R3-proven verbatim. stats[0:128)=mean, [128:256)=rstd.
// ---------------------------------------------------------------------------
__global__ __launch_bounds__(256) void gn_stats_kernel(
    const void* __restrict__ x, const void* __restrict__ w_in,
    float* __restrict__ stats) {
  const bool f32 = detect_f32(w_in);
  const int b = blockIdx.x;
  const size_t base = (size_t)b << 16;
  float s = 0.f, ss = 0.f;
  for (int i = threadIdx.x; i < 65536; i += 256) {
    float v = ld(x, base + i, f32);
    s += v;
    ss += v * v;
  }
  __shared__ float rs[256], rq[256];
  rs[threadIdx.x] = s;
  rq[threadIdx.x] = ss;
  __syncthreads();
  for (int off = 128; off > 0; off >>= 1) {
    if (threadIdx.x < off) {
      rs[threadIdx.x] += rs[threadIdx.x + off];
      rq[threadIdx.x] += rq[threadIdx.x + off];
    }
    __syncthreads();
  }
  if (threadIdx.x == 0) {
    float m = rs[0] * (1.0f / 65536.0f);
    float var = rq[0] * (1.0f / 65536.0f) - m * m;
    stats[b] = m;
    stats[128 + b] = rsqrtf(var + EPSV);
  }
}

// ---------------------------------------------------------------------------
// kv_gemm — THE ONLY CHANGED COMPONENT vs the R3-passing configuration.
// MFMA with dtype-aware staging. Writes proven layout kv[t][0:512)=K,
// [512:1024)=V (bf16 always).
// Grid (4, 128): bx = proj*2 + ehalf; by = 32-row t tile; 4 waves split e by 64.
// MFMA 16x16x32 bf16, D[m][n] = sum_k A[m][k]*B[n][k]:
//   A[m=lane&15][k=quad*8+j] = w_in row (m -> e)
//   B[n=lane&15][k=quad*8+j] = Xn row (n -> t), LDS stride 520
//   C/D: col(n)=lane&15, row(m)=quad*4+reg
// ---------------------------------------------------------------------------
__global__ __launch_bounds__(256) void kv_gemm_kernel(
    const void* __restrict__ x, const void* __restrict__ gsc,
    const void* __restrict__ gbi, const float* __restrict__ stats,
    const void* __restrict__ w_in, const void* __restrict__ b_in,
    unsigned short* __restrict__ kv, int nn) {
  const bool f32 = detect_f32(w_in);
  __shared__ __align__(16) short xn[32 * 520];
  const int tid = threadIdx.x;
  const int wave = tid >> 6, lane = tid & 63, l15 = lane & 15, quad = lane >> 4;
  const int t0 = blockIdx.y * 32;
  const int proj = blockIdx.x >> 1;   // 0 = K, 1 = V
  const int ehalf = blockIdx.x & 1;   // 256-wide e half

  {  // stage GN-normalized Xn rows [t0, t0+32), layout [row][c], stride 520
    const int part = tid & 3, crel = tid >> 2;
    for (int c0 = 0; c0 < 512; c0 += 64) {
      int c = c0 + crel;
      float rr = stats[128 + nn * GROUPS + (c >> 4)];
      float mu = stats[nn * GROUPS + (c >> 4)];
      float scl = ld(gsc, c, f32) * rr;
      float sft = ld(gbi, c, f32) - mu * scl;
      float f[8];
      if (f32) {
        const float4* p = (const float4*)((const float*)x +
                                          ((size_t)(nn * C + c) << 12) + t0 + part * 8);
        float4 r0 = p[0], r1 = p[1];
        f[0] = r0.x; f[1] = r0.y; f[2] = r0.z; f[3] = r0.w;
        f[4] = r1.x; f[5] = r1.y; f[6] = r1.z; f[7] = r1.w;
      } else {
        uint4 raw = *(const uint4*)((const unsigned short*)x +
                                    ((size_t)(nn * C + c) << 12) + t0 + part * 8);
        unpack8(raw, f);
      }
#pragma unroll
      for (int j = 0; j < 8; ++j)
        xn[(part * 8 + j) * 520 + c] = (short)fb(f[j] * scl + sft);
    }
  }
  __syncthreads();

  const int wrow = 512 + proj * 512 + ehalf * 256 + wave * 64;  // w_in/b_in row
  const int cbase = proj * 512 + ehalf * 256 + wave * 64;       // kv column

  f32x4 acc[4][2];
#pragma unroll
  for (int i = 0; i < 4; ++i)
#pragma unroll
    for (int j = 0; j < 2; ++j) acc[i][j] = {0.f, 0.f, 0.f, 0.f};

  for (int kc = 0; kc < 16; ++kc) {
    bf16x8 a[4], b[2];
#pragma unroll
    for (int es = 0; es < 4; ++es) {
      const size_t off = (size_t)(wrow + es * 16 + l15) * 512 + kc * 32 + quad * 8;
      if (f32) {
        const float4* p = (const float4*)((const float*)w_in + off);
        float4 w0 = p[0], w1 = p[1];
        bf16x8 r;
        r[0] = (short)fb(w0.x); r[1] = (short)fb(w0.y);
        r[2] = (short)fb(w0.z); r[3] = (short)fb(w0.w);
        r[4] = (short)fb(w1.x); r[5] = (short)fb(w1.y);
        r[6] = (short)fb(w1.z); r[7] = (short)fb(w1.w);
        a[es] = r;
      } else {
        a[es] = frag_ld((const short*)w_in + off);
      }
    }
#pragma unroll
    for (int ts = 0; ts < 2; ++ts)
      b[ts] = frag_ld(xn + (ts * 16 + l15) * 520 + kc * 32 + quad * 8);
#pragma unroll
    for (int es = 0; es < 4; ++es)
#pragma unroll
      for (int ts = 0; ts < 2; ++ts) acc[es][ts] = MFMA(a[es], b[ts], acc[es][ts]);
  }

#pragma unroll
  for (int es = 0; es < 4; ++es) {
    int bidx = wrow + es * 16 + quad * 4;
    float b0 = ld(b_in, bidx, f32), b1 = ld(b_in, bidx + 1, f32);
    float b2 = ld(b_in, bidx + 2, f32), b3 = ld(b_in, bidx + 3, f32);
    int ecol = cbase + es * 16 + quad * 4;
#pragma unroll
    for (int ts = 0; ts < 2; ++ts) {
      int t = t0 + ts * 16 + l15;
      uint2 u;
      u.x = (unsigned)fb(acc[es][ts][0] + b0) | ((unsigned)fb(acc[es][ts][1] + b1) << 16);
      u.y = (unsigned)fb(acc[es][ts][2] + b2) | ((unsigned)fb(acc[es][ts][3] + b3) << 16);
      *(uint2*)(kv + (size_t)t * 1024 + ecol) = u;
    }
  }
}

// ---------------------------------------------------------------------------
// attn_proj — R3-proven VERBATIM (detection + dual-dtype branches).
// One block per query position s. kv rows: [K(512) | V(512)], bf16.
// ---------------------------------------------------------------------------
__global__ __launch_bounds__(256) void attn_proj_kernel(
    const void* __restrict__ x, const void* __restrict__ gsc,
    const void* __restrict__ gbi, const float* __restrict__ stats,
    const void* __restrict__ w_in, const void* __restrict__ b_in,
    const unsigned short* __restrict__ kv, const void* __restrict__ w_out,
    const void* __restrict__ b_out, void* __restrict__ out, int nn) {
  const bool f32 = detect_f32(w_in);
  const int s = blockIdx.x;
  const int tid = threadIdx.x;
  __shared__ float S[512];
  __shared__ float qrow[512];
  __shared__ float orow[512];
  __shared__ float red[256];
  __shared__ float sc[4096];

  // --- normalized input column S[c] = GN(x[nn][c][s]) ---
#pragma unroll
  for (int half = 0; half < 2; ++half) {
    int c = tid + 256 * half;
    float mu = stats[nn * GROUPS + (c >> 4)];
    float rr = stats[128 + nn * GROUPS + (c >> 4)];
    float v = ld(x, ((size_t)(nn * C + c) << 12) + s, f32);
    S[c] = (v - mu) * rr * ld(gsc, c, f32) + ld(gbi, c, f32);
  }
  __syncthreads();

  // --- q[e] = (S . w_in[e][:] + b_in[e]) * scale, e = tid, tid+256 ---
#pragma unroll
  for (int half = 0; half < 2; ++half) {
    int e = tid + 256 * half;
    float acc = 0.f;
    if (f32) {
      const float4* w4 =
          reinterpret_cast<const float4*>((const float*)w_in + (size_t)e * 512);
      for (int i = 0; i < 128; ++i) {
        float4 w = w4[i];
        acc += w.x * S[4 * i] + w.y * S[4 * i + 1] + w.z * S[4 * i + 2] +
               w.w * S[4 * i + 3];
      }
    } else {
      const uint4* w4 = reinterpret_cast<const uint4*>(
          (const unsigned short*)w_in + (size_t)e * 512);
      for (int i = 0; i < 64; ++i) {
        float f[8];
        unpack8(w4[i], f);
#pragma unroll
        for (int j = 0; j < 8; ++j) acc += f[j] * S[8 * i + j];
      }
    }
    qrow[e] = (acc + ld(b_in, e, f32)) * ATTN_SCALE;
  }
  __syncthreads();

  // --- scores sc[t] = qrow . K[t]  (kv always bf16) ---
#pragma unroll 1
  for (int i = 0; i < 16; ++i) {
    int t = tid + 256 * i;
    const uint4* k4 = reinterpret_cast<const uint4*>(kv + (size_t)t * 1024);
    float acc = 0.f;
#pragma unroll 4
    for (int d = 0; d < 64; ++d) {
      float f[8];
      unpack8(k4[d], f);
#pragma unroll
      for (int j = 0; j < 8; ++j) acc += f[j] * qrow[8 * d + j];
    }
    sc[t] = acc;
  }
  __syncthreads();

  // --- softmax ---
  float m = -3.0e38f;
#pragma unroll
  for (int i = 0; i < 16; ++i) m = fmaxf(m, sc[tid + 256 * i]);
  red[tid] = m;
  __syncthreads();
  for (int off = 128; off > 0; off >>= 1) {
    if (tid < off) red[tid] = fmaxf(red[tid], red[tid + off]);
    __syncthreads();
  }
  m = red[0];
  __syncthreads();
  float lsum = 0.f;
#pragma unroll
  for (int i = 0; i < 16; ++i) {
    int t = tid + 256 * i;
    float e = __expf(sc[t] - m);
    sc[t] = e;
    lsum += e;
  }
  red[tid] = lsum;
  __syncthreads();
  for (int off = 128; off > 0; off >>= 1) {
    if (tid < off) red[tid] += red[tid + off];
    __syncthreads();
  }
  float inv = 1.0f / red[0];
  __syncthreads();
#pragma unroll
  for (int i = 0; i < 16; ++i) sc[tid + 256 * i] *= inv;
  __syncthreads();

  // --- P @ V : thread owns channels tid, tid+256 ---
  {
    float a0 = 0.f, a1 = 0.f;
    const unsigned short* vb = kv + 512;
#pragma unroll 4
    for (int t = 0; t < 4096; ++t) {
      float p = sc[t];
      a0 += p * bf(vb[(size_t)t * 1024 + tid]);
      a1 += p * bf(vb[(size_t)t * 1024 + tid + 256]);
    }
    orow[tid] = a0;
    orow[tid + 256] = a1;
  }
  __syncthreads();

  // --- out[nn][cc][s] = orow . w_out[cc][:] + b_out[cc] + x[nn][cc][s] ---
#pragma unroll
  for (int half = 0; half < 2; ++half) {
    int cc = tid + 256 * half;
    float acc = 0.f;
    if (f32) {
      const float4* w4 = reinterpret_cast<const float4*>((const float*)w_out +
                                                         (size_t)cc * 512);
      for (int i = 0; i < 128; ++i) {
        float4 w = w4[i];
        acc += w.x * orow[4 * i] + w.y * orow[4 * i + 1] +
               w.z * orow[4 * i + 2] + w.w * orow[4 * i + 3];
      }
    } else {
      const uint4* w4 = reinterpret_cast<const uint4*>(
          (const unsigned short*)w_out + (size_t)cc * 512);
      for (int i = 0; i < 64; ++i) {
        float f[8];
        unpack8(w4[i], f);
#pragma unroll
        for (int j = 0; j < 8; ++j) acc += f[j] * orow[8 * i + j];
      }
    }
    size_t oidx = ((size_t)(nn * C + cc) << 12) + s;
    float v = acc + ld(b_out, cc, f32) + ld(x, oidx, f32);
    if (f32)
      ((float*)out)[oidx] = v;
    else
      ((unsigned short*)out)[oidx] = fb(v);
  }
}

// ---------------------------------------------------------------------------
extern "C" void kernel_launch(void* const* d_in, const int* in_sizes, int n_in,
                              void* d_out, int out_size, void* d_ws, size_t ws_size,
                              hipStream_t stream) {
  const void* x = d_in[0];
  const void* gn_scale = d_in[1];
  const void* gn_bias = d_in[2];
  const void* w_in = d_in[3];
  const void* b_in = d_in[4];
  const void* w_out = d_in[5];
  const void* b_out = d_in[6];
  (void)in_sizes; (void)n_in; (void)out_size; (void)ws_size;

  // ws: [stats 1KB | kv bf16 4096x1024 interleaved K|V] = 8.39 MB (R3-proven)
  float* stats = (float*)d_ws;
  unsigned short* kv = (unsigned short*)((char*)d_ws + 1024);

  gn_stats_kernel<<<NBATCH * GROUPS, 256, 0, stream>>>(x, w_in, stats);

  for (int nn = 0; nn < NBATCH; ++nn) {
    kv_gemm_kernel<<<dim3(4, 128), 256, 0, stream>>>(x, gn_scale, gn_bias, stats,
                                                     w_in, b_in, kv, nn);
    attn_proj_kernel<<<HW, 256, 0, stream>>>(x, gn_scale, gn_bias, stats, w_in,
                                             b_in, kv, w_out, b_out, d_out, nn);
  }
}